// Round 8
// baseline (258.222 us; speedup 1.0000x reference)
//
#include <hip/hip_runtime.h>
#include <hip/hip_bf16.h>

typedef __bf16 bf16;
typedef __bf16 bf16x4 __attribute__((ext_vector_type(4)));
typedef __bf16 bf16x8 __attribute__((ext_vector_type(8)));
typedef float f32x4 __attribute__((ext_vector_type(4)));

#define B_ 16
#define N_ 1024
#define F_ 512

__device__ __forceinline__ float rdv(const void* p, size_t i, int f32) {
  return f32 ? ((const float*)p)[i] : (float)((const bf16*)p)[i];
}

// async global->LDS, 16B per lane; LDS dest = wave-uniform base + lane*16
__device__ __forceinline__ void gld16(const bf16* g, bf16* l) {
  __builtin_amdgcn_global_load_lds(
      (const __attribute__((address_space(1))) unsigned int*)g,
      (__attribute__((address_space(3))) unsigned int*)l, 16, 0, 0);
}

// ---------------------------------------------------------------------------
// Merged prep kernel v4.  Per-WAVE dtype flag via ballot (no LDS / no sync).
// Fused blocks [0,2048): {2 Xc chunks + 1 adj tile (128j x 64i)}.
// v4: adj tile processed in TWO 64-row passes over a [64][65] f32 LDS tile
// (17.7 KB total LDS -> 8 blocks/CU = 32 waves, the per-CU cap; v3's 34.3 KB
// capped at 4 blocks/CU -> 30% occupancy, latency-bound at 2.3 TB/s).
// All 8 adj row-loads issue upfront (registers); colsums accumulate in regs
// across passes.  __launch_bounds__(256,8) pins VGPR <= 64 for 32 waves/CU.
//   [0,2048)     fused: Xc chunks 2q,2q+1  +  adj tile -> adjT, csp
//   [2048,2816)  W transposes -> Wt
//   [2816,2822)  bias convert -> bc   (block 2816 publishes flag[0])
// ---------------------------------------------------------------------------
__global__ __launch_bounds__(256, 8)
void k_pre(const void* b1, const void* b2, const void* b3,
           const void* W1, const void* W2, const void* W3,
           const void* X, const void* adj,
           int* __restrict__ flag, float* __restrict__ bc,
           bf16* __restrict__ Wt, bf16* __restrict__ xc,
           bf16* __restrict__ adjT, float* __restrict__ csp) {
  __shared__ float tile[64][65];   // 16.64 KB
  __shared__ float red2[4][64];    // 1 KB
  const int bid = blockIdx.x;
  const int t = threadIdx.x;

  // --- per-wave dtype flag: 4 words/lane from W1[0..255] (L1-hot) ---
  int f;
  {
    const unsigned* w = (const unsigned*)W1;
    const int l = t & 63;
    int c = 0;
#pragma unroll
    for (int i = 0; i < 4; ++i) {
      unsigned v = w[l + 64 * i];
      c += __popcll(__ballot(((v >> 7) & 0xFFu) >= 130u));
    }
    f = c > 64;  // 1 = fp32 inputs
  }

  if (bid < 2048) {
    const int q = bid;
    const int b = q >> 7, rem = q & 127;
    const int j0 = (rem >> 4) << 7, i0 = (rem & 15) << 6;
    const size_t sb = (size_t)b * N_ * N_;
    const int tx = t & 15, jr = t >> 4;  // 16 cols-of-4 x 16 rows/pass-half
    const size_t i8a = ((size_t)(2 * q) * 256 + t) * 8;
    const size_t i8b = ((size_t)(2 * q + 1) * 256 + t) * 8;
    bf16* dst = adjT + sb;
    float scc = 0.f;  // register colsum accumulator (1 col, 32 rows)

    if (f) {
      // ---- issue Xc loads first, then ALL 8 adj row-loads (fp32) ----
      const float* xa = (const float*)X + i8a;
      const float* xb = (const float*)X + i8b;
      f32x4 xv0 = *(const f32x4*)xa;
      f32x4 xv1 = *(const f32x4*)(xa + 4);
      f32x4 xv2 = *(const f32x4*)xb;
      f32x4 xv3 = *(const f32x4*)(xb + 4);
      const float* src = (const float*)adj + sb;
      f32x4 av[8];
#pragma unroll
      for (int s = 0; s < 8; ++s)
        av[s] = *(const f32x4*)&src[(size_t)(j0 + jr + 16 * s) * N_ + i0 + 4 * tx];
      // ---- Xc convert+store (overlaps adj latency) ----
      bf16x8 o0 = {(bf16)xv0[0], (bf16)xv0[1], (bf16)xv0[2], (bf16)xv0[3],
                   (bf16)xv1[0], (bf16)xv1[1], (bf16)xv1[2], (bf16)xv1[3]};
      bf16x8 o1 = {(bf16)xv2[0], (bf16)xv2[1], (bf16)xv2[2], (bf16)xv2[3],
                   (bf16)xv3[0], (bf16)xv3[1], (bf16)xv3[2], (bf16)xv3[3]};
      *(bf16x8*)&xc[i8a] = o0;
      *(bf16x8*)&xc[i8b] = o1;
      // ---- two 64-row passes ----
#pragma unroll
      for (int p = 0; p < 2; ++p) {
        if (p) __syncthreads();  // WAR: pass-0 reads done before refill
#pragma unroll
        for (int s = 0; s < 4; ++s)
          *(f32x4*)&tile[jr + 16 * s][4 * tx] = av[4 * p + s];
        __syncthreads();
        {  // colsum partial: thread owns col (t&63), rows g*16..g*16+15
          const int cc = t & 63, g = t >> 6;
#pragma unroll
          for (int rr = 0; rr < 16; ++rr) scc += tile[g * 16 + rr][cc];
        }
        {  // transposed write: 64 i-rows x 64 j-cols, bf16x8 stores
          const int oct = t & 7;
#pragma unroll
          for (int s2 = 0; s2 < 2; ++s2) {
            const int ii = (t >> 3) + 32 * s2;
            bf16x8 o;
#pragma unroll
            for (int u = 0; u < 8; ++u) o[u] = (bf16)tile[8 * oct + u][ii];
            *(bf16x8*)&dst[(size_t)(i0 + ii) * N_ + j0 + 64 * p + 8 * oct] = o;
          }
        }
      }
    } else {
      // ---- bf16 path: Xc bitcopy; adj loads bf16x4 ----
      f32x4 xv0 = *(const f32x4*)((const bf16*)X + i8a);
      f32x4 xv1 = *(const f32x4*)((const bf16*)X + i8b);
      const bf16* src = (const bf16*)adj + sb;
      bf16x4 av[8];
#pragma unroll
      for (int s = 0; s < 8; ++s)
        av[s] = *(const bf16x4*)&src[(size_t)(j0 + jr + 16 * s) * N_ + i0 + 4 * tx];
      *(f32x4*)&xc[i8a] = xv0;
      *(f32x4*)&xc[i8b] = xv1;
#pragma unroll
      for (int p = 0; p < 2; ++p) {
        if (p) __syncthreads();
#pragma unroll
        for (int s = 0; s < 4; ++s) {
          bf16x4 a = av[4 * p + s];
          *(f32x4*)&tile[jr + 16 * s][4 * tx] =
              (f32x4){(float)a[0], (float)a[1], (float)a[2], (float)a[3]};
        }
        __syncthreads();
        {
          const int cc = t & 63, g = t >> 6;
#pragma unroll
          for (int rr = 0; rr < 16; ++rr) scc += tile[g * 16 + rr][cc];
        }
        {
          const int oct = t & 7;
#pragma unroll
          for (int s2 = 0; s2 < 2; ++s2) {
            const int ii = (t >> 3) + 32 * s2;
            bf16x8 o;
#pragma unroll
            for (int u = 0; u < 8; ++u) o[u] = (bf16)tile[8 * oct + u][ii];
            *(bf16x8*)&dst[(size_t)(i0 + ii) * N_ + j0 + 64 * p + 8 * oct] = o;
          }
        }
      }
    }
    __syncthreads();
    red2[t >> 6][t & 63] = scc;
    __syncthreads();
    if (t < 64)
      csp[((size_t)(j0 >> 7) * B_ + b) * N_ + i0 + t] =
          red2[0][t] + red2[1][t] + red2[2][t] + red2[3][t];
  } else if (bid < 2816) {
    // ---- W transpose through a 32x32 sub-tile (stride-65 rows) ----
    const int bid2 = bid - 2048;
    const int z = bid2 >> 8, ti = bid2 & 255;
    const int f0 = (ti & 15) * 32, k0 = (ti >> 4) * 32;
    const int tx = t & 31, ty = t >> 5;
    const void* W = (z == 0) ? W1 : ((z == 1) ? W2 : W3);
    bf16* dst = Wt + (size_t)z * F_ * F_;
#pragma unroll
    for (int s = 0; s < 4; ++s)
      tile[ty + 8 * s][tx] = rdv(W, (size_t)(k0 + ty + 8 * s) * F_ + f0 + tx, f);
    __syncthreads();
#pragma unroll
    for (int s = 0; s < 4; ++s)
      dst[(size_t)(f0 + ty + 8 * s) * F_ + k0 + tx] = (bf16)tile[tx][ty + 8 * s];
  } else {
    // ---- bias convert ----
    const int j = (bid - 2816) * 256 + t;  // 0..1535
    const void* src = (j < 512) ? b1 : (j < 1024 ? b2 : b3);
    bc[j] = rdv(src, (size_t)(j & 511), f);
    if (bid == 2816 && t == 0) flag[0] = f;
  }
}

// degree scale r = colsum^-1/2 (0 if <=0), colsum = sum of 8 csp slices
__device__ __forceinline__ float rscale(const float* __restrict__ csp, int b, int node) {
  float c = 0.f;
#pragma unroll
  for (int z = 0; z < 8; ++z) c += csp[((size_t)z * B_ + b) * N_ + node];
  return c > 0.f ? rsqrtf(c) : 0.f;
}

// C[M][Nc] = A[M][K] * Bt[Nc][K]^T, with optional column scale (SCALEN:
// v *= r_n), row scale (SCALEM: v = r_m*v), bias, ReLU.  128x128 tile, BK=64,
// double-buffered LDS, raw s_barrier pipeline w/ fine-grained vmcnt.
// 1-D grid, XCD swizzle: id%8 = XCD, 2 batches per XCD, 32 tiles per batch.
// (Proven best-measured structure: 2 blocks/CU co-residency.)
template <int BIAS, int RELU, int OUTDYN, int SCALEN, int SCALEM, int GX>
__global__ __launch_bounds__(256)
void k_gemm_bt(const bf16* __restrict__ A, const bf16* __restrict__ Bt,
               const float* __restrict__ bias, void* __restrict__ C,
               const int* __restrict__ flag, const float* __restrict__ csp,
               int Nc, int K, long sA, long sB, long sC) {
  __shared__ __align__(16) char smem[65536];  // 2 x (As 16KB + Bs 16KB)
  const int id = blockIdx.x;
  const int xcd = id & 7, p = id >> 3;
  const int bz = xcd * 2 + (p >> 5);
  const int tl = p & 31;
  const int bx = tl % GX, by = tl / GX;

  const int tid = threadIdx.x;
  const int wid = tid >> 6, lane = tid & 63;
  const int wm = wid >> 1, wn = wid & 1;
  const int quad = lane >> 4, l16 = lane & 15;
  const int rl = lane >> 3;               // 0..7 staging row within 8-row issue
  const int cg8 = ((lane & 7) ^ rl) * 8;  // swizzled global col offset (elems)
  const int h = l16 & 7;                  // fragment-read swizzle key

  const bf16* gA = A + (size_t)bz * sA + (size_t)by * 128 * K;
  const bf16* gB = Bt + (size_t)bz * sB + (size_t)bx * 128 * K;

  f32x4 acc[4][4];
#pragma unroll
  for (int i = 0; i < 4; ++i)
#pragma unroll
    for (int j = 0; j < 4; ++j) acc[i][j] = (f32x4){0.f, 0.f, 0.f, 0.f};

  auto stage = [&](int d, int k0) {
    bf16* As = (bf16*)(smem + d * 32768);
    bf16* Bs = (bf16*)(smem + d * 32768 + 16384);
#pragma unroll
    for (int i = 0; i < 4; ++i) {
      const int r0 = wid * 32 + i * 8;  // wave-uniform LDS row base
      gld16(gA + (size_t)(r0 + rl) * K + k0 + cg8, &As[r0 * 64]);
      gld16(gB + (size_t)(r0 + rl) * K + k0 + cg8, &Bs[r0 * 64]);
    }
  };

  stage(0, 0);
  for (int k0 = 0; k0 < K; k0 += 64) {
    const int cur = (k0 >> 6) & 1;
    if (k0 + 64 < K) {
      stage(1 - cur, k0 + 64);
      asm volatile("s_waitcnt vmcnt(8)\n\ts_barrier" ::: "memory");
    } else {
      asm volatile("s_waitcnt vmcnt(0)\n\ts_barrier" ::: "memory");
    }
    const bf16* As = (const bf16*)(smem + cur * 32768);
    const bf16* Bs = (const bf16*)(smem + cur * 32768 + 16384);
#pragma unroll
    for (int s = 0; s < 2; ++s) {
      bf16x8 af[4], bfv[4];
#pragma unroll
      for (int tm = 0; tm < 4; ++tm)
        af[tm] = *(const bf16x8*)&As[(wm * 64 + tm * 16 + l16) * 64 +
                                     (((quad + 4 * s) ^ h) * 8)];
#pragma unroll
      for (int tn = 0; tn < 4; ++tn)
        bfv[tn] = *(const bf16x8*)&Bs[(wn * 64 + tn * 16 + l16) * 64 +
                                      (((quad + 4 * s) ^ h) * 8)];
#pragma unroll
      for (int tm = 0; tm < 4; ++tm)
#pragma unroll
        for (int tn = 0; tn < 4; ++tn)
          acc[tm][tn] =
              __builtin_amdgcn_mfma_f32_16x16x32_bf16(af[tm], bfv[tn], acc[tm][tn], 0, 0, 0);
    }
    asm volatile("s_barrier" ::: "memory");  // WAR protect (exec barrier only)
  }

  // per-block scale table (128 rows or cols) in LDS (K-loop LDS now free)
  float* rsh = (float*)(smem + 37376);  // repack region ends at 36864
  if (SCALEN || SCALEM) {
    if (tid < 128) {
      const int node = (SCALEM ? by * 128 : bx * 128) + tid;
      rsh[tid] = rscale(csp, bz, node);
    }
    __syncthreads();
  }

  // C/D layout: col = lane&15, row = quad*4 + reg  [m89/m91]
  const size_t cb = (size_t)bz * sC;
  const int mb_w = by * 128 + wm * 64;
  const int nb_w = bx * 128 + wn * 64;

  if (OUTDYN) {
    const int of32 = flag[0];
#pragma unroll
    for (int tn = 0; tn < 4; ++tn) {
      const int n = nb_w + tn * 16 + l16;
      float bv = BIAS ? bias[n] : 0.f;
      const float cscale = SCALEN ? rsh[wn * 64 + tn * 16 + l16] : 1.f;
#pragma unroll
      for (int tm = 0; tm < 4; ++tm) {
        const int m0 = mb_w + tm * 16 + quad * 4;
#pragma unroll
        for (int r = 0; r < 4; ++r) {
          float v = acc[tm][tn][r];
          if (SCALEM) v *= rsh[wm * 64 + tm * 16 + quad * 4 + r];
          if (SCALEN) v *= cscale;
          v += bv;
          if (RELU) v = v > 0.f ? v : 0.f;
          const size_t idx = cb + (size_t)(m0 + r) * Nc + n;
          if (of32) ((float*)C)[idx] = v;
          else      ((bf16*)C)[idx] = (bf16)v;
        }
      }
    }
  } else {
    // repack through per-wave LDS tile [64][72], then 16B coalesced stores
    bf16* W = (bf16*)smem + wid * (64 * 72);
#pragma unroll
    for (int tn = 0; tn < 4; ++tn) {
      const int n = nb_w + tn * 16 + l16;
      float bv = BIAS ? bias[n] : 0.f;
      const float cscale = SCALEN ? rsh[wn * 64 + tn * 16 + l16] : 1.f;
#pragma unroll
      for (int tm = 0; tm < 4; ++tm) {
#pragma unroll
        for (int r = 0; r < 4; ++r) {
          float v = acc[tm][tn][r];
          if (SCALEM) v *= rsh[wm * 64 + tm * 16 + quad * 4 + r];
          if (SCALEN) v *= cscale;
          v += bv;
          if (RELU) v = v > 0.f ? v : 0.f;
          W[(tm * 16 + quad * 4 + r) * 72 + tn * 16 + l16] = (bf16)v;
        }
      }
    }
    bf16* gC = (bf16*)C + cb;
#pragma unroll
    for (int i = 0; i < 8; ++i) {
      const int row = i * 8 + rl;
      bf16x8 v = *(const bf16x8*)&W[row * 72 + (lane & 7) * 8];
      *(bf16x8*)&gC[(size_t)(mb_w + row) * Nc + nb_w + (lane & 7) * 8] = v;
    }
  }
}

extern "C" void kernel_launch(void* const* d_in, const int* in_sizes, int n_in,
                              void* d_out, int out_size, void* d_ws, size_t ws_size,
                              hipStream_t stream) {
  // ws: csp(512KB used of 1MB) | flag | bc | adjT(32MB) | Wt(1.5MB) | Zt(16MB)
  char* ws = (char*)d_ws;
  float* csp  = (float*)ws;                         // [8][B][N] fp32
  int*  flag  = (int*)(ws + 1048576);
  float* bc   = (float*)(ws + 1048832);             // 6 KB [3][512]
  bf16* adjT  = (bf16*)(ws + 1056768);              // 32 MB [B][N][N]
  bf16* Wt    = (bf16*)(ws + 1056768 + 33554432);   // 1.5 MB [3][F][F]
  bf16* Zt    = (bf16*)(ws + 1056768 + 33554432 + 3 * F_ * F_ * 2);  // 16 MB
  bf16* Xc = (bf16*)d_out;  // d_out doubles as bf16 activation scratch

  const long sW = 0;
  const long sX = (long)N_ * F_;
  const long sZ = (long)F_ * N_;
  const long sAn = (long)N_ * N_;

  // one merged prep dispatch: fused {2xXc + tran} x2048 + Wt(768) + bias(6)
  k_pre<<<2048 + 768 + 6, 256, 0, stream>>>(
      d_in[3], d_in[5], d_in[7], d_in[2], d_in[4], d_in[6], d_in[0], d_in[1],
      flag, bc, Wt, Xc, adjT, csp);

  // GEMM1: Zt = Wt_z @ Xc^T, cols scaled by r_j   (M=F, Nc=N, K=F, GX=8)
  // GEMM2: X' = r_i * (adjT @ Zt^T) + b, ReLU     (M=N, Nc=F, K=N, GX=4)
  // layer 1
  k_gemm_bt<0, 0, 0, 1, 0, 8><<<512, 256, 0, stream>>>(Wt,               Xc, nullptr,   Zt, flag, csp, N_, F_, sW, sX, sZ);
  k_gemm_bt<1, 1, 0, 0, 1, 4><<<512, 256, 0, stream>>>(adjT,             Zt, bc,        Xc, flag, csp, F_, N_, sAn, sZ, sX);
  // layer 2
  k_gemm_bt<0, 0, 0, 1, 0, 8><<<512, 256, 0, stream>>>(Wt + F_ * F_,     Xc, nullptr,   Zt, flag, csp, N_, F_, sW, sX, sZ);
  k_gemm_bt<1, 1, 0, 0, 1, 4><<<512, 256, 0, stream>>>(adjT,             Zt, bc + 512,  Xc, flag, csp, F_, N_, sAn, sZ, sX);
  // layer 3
  k_gemm_bt<0, 0, 0, 1, 0, 8><<<512, 256, 0, stream>>>(Wt + 2 * F_ * F_, Xc, nullptr,   Zt, flag, csp, N_, F_, sW, sX, sZ);
  k_gemm_bt<1, 0, 1, 0, 1, 4><<<512, 256, 0, stream>>>(adjT,             Zt, bc + 1024, d_out, flag, csp, F_, N_, sAn, sZ, sX);
}